// Round 1
// baseline (2154.270 us; speedup 1.0000x reference)
//
#include <hip/hip_runtime.h>
#include <math.h>

// Problem constants (fixed by reference): B=4, S=1024, D=1024, H=16, DK=64
#define NTOK 4096            // B*S
// head-split layout: [B,H,S,DK], addr = ((b*16+h)<<16) + (s<<6) + dk

__device__ __forceinline__ int split_idx(int n, int d) {
  // token n (= b*1024+s), dim d (= h*64+dk) -> [B,H,S,DK] flat index
  int b = n >> 10, s = n & 1023, h = d >> 6, dk = d & 63;
  return (((b << 4) + h) << 16) + (s << 6) + dk;
}

struct GemmPtrs {
  const float* x[6];
  const float* w[6];
  const float* b[6];
  float* y[6];
};

// ---------------------------------------------------------------------------
// fp32 GEMM: Y[n,o] = sum_d X[n,d] * W[o,d] + b[o]
// M=4096, N=1024, K=1024. BM=BN=128, BK=16, 256 threads, 8x8 per thread.
// ---------------------------------------------------------------------------
template<bool SPLIT_IN, bool SPLIT_OUT>
__global__ __launch_bounds__(256, 4) void gemm_kernel(GemmPtrs P) {
  const int z = blockIdx.z;
  const float* __restrict__ A    = P.x[z];
  const float* __restrict__ W    = P.w[z];
  const float* __restrict__ bias = P.b[z];
  float* __restrict__ Y          = P.y[z];

  __shared__ float As[16][132];   // k-major, padded: reads conflict-free
  __shared__ float Bs[16][132];

  const int t  = threadIdx.x;
  const int tx = t & 15, ty = t >> 4;
  const int bm0 = blockIdx.y * 128;
  const int bn0 = blockIdx.x * 128;

  float acc[8][8];
#pragma unroll
  for (int ii = 0; ii < 8; ++ii)
#pragma unroll
    for (int jj = 0; jj < 8; ++jj) acc[ii][jj] = 0.f;

  for (int k0 = 0; k0 < 1024; k0 += 16) {
    float4 av[2], bv[2];
#pragma unroll
    for (int q = 0; q < 2; ++q) {
      const int f   = q * 256 + t;   // float4 id 0..511; 4 f4 per row of 16
      const int row = f >> 2;        // 0..127
      const int k4  = f & 3;
      const int gk  = k0 + k4 * 4;
      if constexpr (SPLIT_IN)
        av[q] = *(const float4*)&A[split_idx(bm0 + row, gk)];
      else
        av[q] = *(const float4*)&A[(bm0 + row) * 1024 + gk];
      bv[q] = *(const float4*)&W[(bn0 + row) * 1024 + gk];
    }
    __syncthreads();
#pragma unroll
    for (int q = 0; q < 2; ++q) {
      const int f   = q * 256 + t;
      const int row = f >> 2;
      const int k4  = f & 3;
      As[k4 * 4 + 0][row] = av[q].x; As[k4 * 4 + 1][row] = av[q].y;
      As[k4 * 4 + 2][row] = av[q].z; As[k4 * 4 + 3][row] = av[q].w;
      Bs[k4 * 4 + 0][row] = bv[q].x; Bs[k4 * 4 + 1][row] = bv[q].y;
      Bs[k4 * 4 + 2][row] = bv[q].z; Bs[k4 * 4 + 3][row] = bv[q].w;
    }
    __syncthreads();
#pragma unroll
    for (int k = 0; k < 16; ++k) {
      const float4 a0 = *(const float4*)&As[k][ty * 4];
      const float4 a1 = *(const float4*)&As[k][64 + ty * 4];
      const float4 b0 = *(const float4*)&Bs[k][tx * 4];
      const float4 b1 = *(const float4*)&Bs[k][64 + tx * 4];
      const float am[8] = {a0.x, a0.y, a0.z, a0.w, a1.x, a1.y, a1.z, a1.w};
      const float bn[8] = {b0.x, b0.y, b0.z, b0.w, b1.x, b1.y, b1.z, b1.w};
#pragma unroll
      for (int ii = 0; ii < 8; ++ii)
#pragma unroll
        for (int jj = 0; jj < 8; ++jj)
          acc[ii][jj] = fmaf(am[ii], bn[jj], acc[ii][jj]);
    }
  }

  const float4 bia0 = *(const float4*)&bias[bn0 + tx * 4];
  const float4 bia1 = *(const float4*)&bias[bn0 + 64 + tx * 4];
  const float bb[8] = {bia0.x, bia0.y, bia0.z, bia0.w,
                       bia1.x, bia1.y, bia1.z, bia1.w};
#pragma unroll
  for (int ii = 0; ii < 8; ++ii) {
    const int m = bm0 + ((ii < 4) ? (ty * 4 + ii) : (64 + ty * 4 + ii - 4));
    float4 r0, r1;
    r0.x = acc[ii][0] + bb[0]; r0.y = acc[ii][1] + bb[1];
    r0.z = acc[ii][2] + bb[2]; r0.w = acc[ii][3] + bb[3];
    r1.x = acc[ii][4] + bb[4]; r1.y = acc[ii][5] + bb[5];
    r1.z = acc[ii][6] + bb[6]; r1.w = acc[ii][7] + bb[7];
    if constexpr (SPLIT_OUT) {
      *(float4*)&Y[split_idx(m, bn0 + tx * 4)]      = r0;
      *(float4*)&Y[split_idx(m, bn0 + 64 + tx * 4)] = r1;
    } else {
      *(float4*)&Y[m * 1024 + bn0 + tx * 4]      = r0;
      *(float4*)&Y[m * 1024 + bn0 + 64 + tx * 4] = r1;
    }
  }
}

// ---------------------------------------------------------------------------
// Fused decay attention. Grid: (S/8, B*H, 2 paths). Block: 512 (8 waves).
// Wave w owns query row i = blockIdx.x*8 + w. DK = 64 = lane count.
// ---------------------------------------------------------------------------
__global__ __launch_bounds__(512, 4) void decay_attn_kernel(
    const float* __restrict__ qm, const float* __restrict__ km,
    const float* __restrict__ vm, const float* __restrict__ qc,
    const float* __restrict__ kc, const float* __restrict__ vc,
    float* __restrict__ om, float* __restrict__ oc,
    const float* __restrict__ gammas) {
  __shared__ float sc[8][1024];    // per-wave score row (raw scores, then p2)
  __shared__ float kvT[64][65];    // transposed K/V chunk: kvT[d][j_local]

  const int t    = threadIdx.x;
  const int lane = t & 63;
  const int w    = t >> 6;
  const int bh   = blockIdx.y;     // b*16 + h
  const int h    = bh & 15;
  const int r0   = blockIdx.x * 8;
  const int i    = r0 + w;         // this wave's query row
  const int path = blockIdx.z;

  const int base = bh << 16;       // bh * S * DK
  const float* Q = (path ? qc : qm) + base;
  const float* K = (path ? kc : km) + base;
  const float* V = (path ? vc : vm) + base;
  float* O       = (path ? oc : om) + base;

  const float g = -log1pf(__expf(gammas[h]));   // gamma_val (< 0)

  // q row into registers (wave-uniform address -> broadcast load)
  float4 qreg[16];
#pragma unroll
  for (int d4 = 0; d4 < 16; ++d4)
    qreg[d4] = *(const float4*)&Q[i * 64 + d4 * 4];

  const int nchunks = (r0 >> 6) + 1;   // chunks of 64 keys covering j <= r0+7

  // ---- phase 1: scores ----
  for (int c = 0; c < 16; ++c) {
    if (c >= nchunks) break;
    const int j0 = c << 6;
#pragma unroll
    for (int p = 0; p < 2; ++p) {
      const int f   = p * 512 + t;   // f4 id 0..1023; 16 f4 per key row
      const int row = f >> 4;
      const int c4  = f & 15;
      const float4 val = *(const float4*)&K[(j0 + row) * 64 + c4 * 4];
      kvT[c4 * 4 + 0][row] = val.x; kvT[c4 * 4 + 1][row] = val.y;
      kvT[c4 * 4 + 2][row] = val.z; kvT[c4 * 4 + 3][row] = val.w;
    }
    __syncthreads();
    float dot = 0.f;
#pragma unroll
    for (int d4 = 0; d4 < 16; ++d4) {
      dot = fmaf(qreg[d4].x, kvT[d4 * 4 + 0][lane], dot);
      dot = fmaf(qreg[d4].y, kvT[d4 * 4 + 1][lane], dot);
      dot = fmaf(qreg[d4].z, kvT[d4 * 4 + 2][lane], dot);
      dot = fmaf(qreg[d4].w, kvT[d4 * 4 + 3][lane], dot);
    }
    sc[w][j0 + lane] = dot * 0.125f;   // 1/sqrt(64)
    __syncthreads();
  }

  // ---- phase 2: decay softmax (wave-local, j = tt*64 + lane) ----
  float v[16], cum[16];
#pragma unroll
  for (int tt = 0; tt < 16; ++tt) v[tt] = sc[w][tt * 64 + lane];

  float m1 = -INFINITY;
#pragma unroll
  for (int tt = 0; tt < 16; ++tt) {
    const bool valid = (tt * 64 + lane) <= i;
    m1 = fmaxf(m1, valid ? v[tt] : -INFINITY);
  }
#pragma unroll
  for (int off = 32; off > 0; off >>= 1) m1 = fmaxf(m1, __shfl_xor(m1, off));

  float z1 = 0.f;
#pragma unroll
  for (int tt = 0; tt < 16; ++tt) {
    const bool valid = (tt * 64 + lane) <= i;
    const float e = __expf(v[tt] - m1);
    z1 += valid ? e : 0.f;
  }
#pragma unroll
  for (int off = 32; off > 0; off >>= 1) z1 += __shfl_xor(z1, off);
  const float rz1 = 1.f / z1;

  // inclusive cumsum of p over the row (16 sequential 64-lane scans)
  float run = 0.f;
#pragma unroll
  for (int tt = 0; tt < 16; ++tt) {
    const bool valid = (tt * 64 + lane) <= i;
    float x = valid ? __expf(v[tt] - m1) * rz1 : 0.f;
#pragma unroll
    for (int off = 1; off < 64; off <<= 1) {
      const float nb = __shfl_up(x, off);
      if (lane >= off) x += nb;
    }
    cum[tt] = run + x;
    run += __shfl(x, 63);
  }
  const float tot = run;

  float m2 = -INFINITY;
#pragma unroll
  for (int tt = 0; tt < 16; ++tt) {
    const int j = tt * 64 + lane;
    const bool valid = j <= i;
    const float rem  = fmaxf(tot - cum[tt], 0.f);
    const float dist = sqrtf(fmaxf(rem * (float)(i - j), 0.f));
    float eff = __expf(dist * g);
    eff = fminf(fmaxf(eff, 1e-5f), 1e5f);
    v[tt] = valid ? v[tt] * eff : -INFINITY;
    m2 = fmaxf(m2, v[tt]);
  }
#pragma unroll
  for (int off = 32; off > 0; off >>= 1) m2 = fmaxf(m2, __shfl_xor(m2, off));

  float z2 = 0.f;
#pragma unroll
  for (int tt = 0; tt < 16; ++tt) {
    const float e = __expf(v[tt] - m2);   // invalid: exp(-inf) = 0
    v[tt] = e;
    z2 += e;
  }
#pragma unroll
  for (int off = 32; off > 0; off >>= 1) z2 += __shfl_xor(z2, off);
  const float rz2 = 1.f / z2;

#pragma unroll
  for (int tt = 0; tt < 16; ++tt) sc[w][tt * 64 + lane] = v[tt] * rz2;

  // ---- phase 3: PV (lane = output dim d) ----
  float acc = 0.f;
  for (int c = 0; c < 16; ++c) {
    if (c >= nchunks) break;
    const int j0 = c << 6;
    __syncthreads();   // previous kvT consumers done
#pragma unroll
    for (int p = 0; p < 2; ++p) {
      const int f   = p * 512 + t;
      const int row = f >> 4;
      const int c4  = f & 15;
      const float4 val = *(const float4*)&V[(j0 + row) * 64 + c4 * 4];
      kvT[c4 * 4 + 0][row] = val.x; kvT[c4 * 4 + 1][row] = val.y;
      kvT[c4 * 4 + 2][row] = val.z; kvT[c4 * 4 + 3][row] = val.w;
    }
    __syncthreads();
#pragma unroll
    for (int q4 = 0; q4 < 16; ++q4) {
      const float4 p4 = *(const float4*)&sc[w][j0 + q4 * 4];  // broadcast
      acc = fmaf(p4.x, kvT[lane][q4 * 4 + 0], acc);
      acc = fmaf(p4.y, kvT[lane][q4 * 4 + 1], acc);
      acc = fmaf(p4.z, kvT[lane][q4 * 4 + 2], acc);
      acc = fmaf(p4.w, kvT[lane][q4 * 4 + 3], acc);
    }
  }
  O[i * 64 + lane] = acc;
}

// ---------------------------------------------------------------------------
extern "C" void kernel_launch(void* const* d_in, const int* in_sizes, int n_in,
                              void* d_out, int out_size, void* d_ws,
                              size_t ws_size, hipStream_t stream) {
  (void)in_sizes; (void)n_in; (void)out_size; (void)ws_size;

  const float* qmean = (const float*)d_in[0];
  const float* qcov  = (const float*)d_in[1];
  const float* kmean = (const float*)d_in[2];
  const float* kcov  = (const float*)d_in[3];
  const float* vmean = (const float*)d_in[4];
  const float* vcov  = (const float*)d_in[5];
  // d_in[6] = mask: fixed causal tril, handled analytically
  const float* wq_m = (const float*)d_in[7];
  const float* bq_m = (const float*)d_in[8];
  const float* wq_c = (const float*)d_in[9];
  const float* bq_c = (const float*)d_in[10];
  const float* wk_m = (const float*)d_in[11];
  const float* bk_m = (const float*)d_in[12];
  const float* wk_c = (const float*)d_in[13];
  const float* bk_c = (const float*)d_in[14];
  const float* wv_m = (const float*)d_in[15];
  const float* bv_m = (const float*)d_in[16];
  const float* wv_c = (const float*)d_in[17];
  const float* bv_c = (const float*)d_in[18];
  const float* wo_m = (const float*)d_in[19];
  const float* bo_m = (const float*)d_in[20];
  const float* wo_c = (const float*)d_in[21];
  const float* bo_c = (const float*)d_in[22];
  const float* gam  = (const float*)d_in[23];

  float* ws = (float*)d_ws;
  const size_t NE = (size_t)NTOK * 1024;   // 4M floats per [B,S,D] tensor
  float* qm = ws + 0 * NE;
  float* qc = ws + 1 * NE;
  float* km = ws + 2 * NE;
  float* kc = ws + 3 * NE;
  float* vm = ws + 4 * NE;
  float* vc = ws + 5 * NE;
  float* om = ws + 6 * NE;
  float* oc = ws + 7 * NE;   // total ws use: 128 MB

  float* out_mean = (float*)d_out;
  float* out_cov  = out_mean + NE;

  GemmPtrs Pin = {};
  Pin.x[0] = qmean; Pin.w[0] = wq_m; Pin.b[0] = bq_m; Pin.y[0] = qm;
  Pin.x[1] = qcov;  Pin.w[1] = wq_c; Pin.b[1] = bq_c; Pin.y[1] = qc;
  Pin.x[2] = kmean; Pin.w[2] = wk_m; Pin.b[2] = bk_m; Pin.y[2] = km;
  Pin.x[3] = kcov;  Pin.w[3] = wk_c; Pin.b[3] = bk_c; Pin.y[3] = kc;
  Pin.x[4] = vmean; Pin.w[4] = wv_m; Pin.b[4] = bv_m; Pin.y[4] = vm;
  Pin.x[5] = vcov;  Pin.w[5] = wv_c; Pin.b[5] = bv_c; Pin.y[5] = vc;

  dim3 gin(8, 32, 6);
  gemm_kernel<false, true><<<gin, 256, 0, stream>>>(Pin);

  dim3 ga(128, 64, 2);
  decay_attn_kernel<<<ga, 512, 0, stream>>>(qm, km, vm, qc, kc, vc, om, oc,
                                            gam);

  GemmPtrs Pout = {};
  Pout.x[0] = om; Pout.w[0] = wo_m; Pout.b[0] = bo_m; Pout.y[0] = out_mean;
  Pout.x[1] = oc; Pout.w[1] = wo_c; Pout.b[1] = bo_c; Pout.y[1] = out_cov;

  dim3 gout(8, 32, 2);
  gemm_kernel<true, false><<<gout, 256, 0, stream>>>(Pout);
}

// Round 2
// 1365.300 us; speedup vs baseline: 1.5779x; 1.5779x over previous
//
#include <hip/hip_runtime.h>
#include <math.h>

// B=4, S=1024, D=1024, H=16, DK=64.  NTOK = B*S.
#define NTOK 4096
typedef unsigned int uint;

// head-split layout: [B,H,S,DK], elem = ((b*16+h)<<16) + (s<<6) + dk
__device__ __forceinline__ int split_idx(int n, int d) {
  int b = n >> 10, s = n & 1023, h = d >> 6, dk = d & 63;
  return (((b << 4) + h) << 16) + (s << 6) + dk;
}

__device__ __forceinline__ ushort bf16_rne(float f) {
  uint u = __float_as_uint(f);
  return (ushort)((u + 0x7FFFu + ((u >> 16) & 1u)) >> 16);
}
__device__ __forceinline__ float bf16f(ushort h) {
  return __uint_as_float(((uint)h) << 16);
}

typedef __attribute__((ext_vector_type(8))) short bf16x8;
typedef __attribute__((ext_vector_type(4))) float f32x4;

__device__ __forceinline__ void gload16(const void* g, void* l) {
  __builtin_amdgcn_global_load_lds(
      (const __attribute__((address_space(1))) void*)g,
      (__attribute__((address_space(3))) void*)l, 16, 0, 0);
}

// ---------------------------------------------------------------------------
// fp32 -> (bf16 hi, bf16 lo) split conversion.  z = tensor id.
// ---------------------------------------------------------------------------
struct ConvP {
  const float4* s[14];
  ushort* hi[14];
  ushort* lo[14];
  int n4[14];
};
__global__ __launch_bounds__(256) void convert_split(ConvP C) {
  const int z = blockIdx.z;
  const int id = blockIdx.x * 256 + threadIdx.x;
  if (id >= C.n4[z]) return;
  const float4 x = C.s[z][id];
  const float xs[4] = {x.x, x.y, x.z, x.w};
  ushort hs[4], ls[4];
#pragma unroll
  for (int k = 0; k < 4; ++k) {
    hs[k] = bf16_rne(xs[k]);
    ls[k] = bf16_rne(xs[k] - bf16f(hs[k]));  // exact residual (Sterbenz)
  }
  ushort4 hv; hv.x = hs[0]; hv.y = hs[1]; hv.z = hs[2]; hv.w = hs[3];
  ushort4 lv; lv.x = ls[0]; lv.y = ls[1]; lv.z = ls[2]; lv.w = ls[3];
  *(ushort4*)&C.hi[z][id * 4] = hv;
  *(ushort4*)&C.lo[z][id * 4] = lv;
}

// ---------------------------------------------------------------------------
// Split-bf16 MFMA GEMM: Y[m,n] = sum_k X[m,k]*W[n,k] + b[n]
//   X = Xhi+Xlo, W = Whi+Wlo; Y ≈ Xhi·Whi + Xhi·Wlo + Xlo·Whi  (fp32-accurate)
// 128x128 tile, BK=32, 256 thr (4 waves 2x2 of 64x64), 16x16x32 bf16 MFMA.
// LDS tiles written linearly by global_load_lds; frag reads conflict-free via
// XOR of the 16B-chunk index with (row>>1)&3, applied on the GLOBAL source.
// ---------------------------------------------------------------------------
struct MG {
  const char* ah[6]; const char* al[6];
  const char* bh[6]; const char* bl[6];
  const float* bias[6]; float* y[6];
};

template<bool SPLIT_IN, bool SPLIT_OUT>
__global__ __launch_bounds__(256, 3) void gemm_mfma(MG P) {
  __shared__ ushort sAhi[4096], sAlo[4096], sBhi[4096], sBlo[4096];  // 4x8KB
  const int z = blockIdx.z;
  const char* __restrict__ Ah = P.ah[z];
  const char* __restrict__ Al = P.al[z];
  const char* __restrict__ Bh = P.bh[z];
  const char* __restrict__ Bl = P.bl[z];

  const int t = threadIdx.x, l = t & 63, w = t >> 6;
  const int wm = w >> 1, wn = w & 1;
  const int bn0 = blockIdx.x * 128, bm0 = blockIdx.y * 128;

  // staging source offsets (bytes), lane-constant part
  int offA[2], offB[2];
  {
    const int srow = w * 16 + (l >> 2), scd = l & 3;
#pragma unroll
    for (int q = 0; q < 2; ++q) {
      const int r = srow + q * 64;
      const int cc = scd ^ ((r >> 1) & 3);  // swizzled 16B chunk in 64B row
      const int m = bm0 + r, n = bn0 + r;
      offA[q] = SPLIT_IN
                    ? ((((m >> 10) << 20) + ((m & 1023) << 6) + cc * 8) * 2)
                    : (m * 2048 + cc * 16);
      offB[q] = n * 2048 + cc * 16;
    }
  }
  // fragment LDS offsets (bytes), constant across K-steps
  int aoff[4], boff[4];
  {
    const int frow = l & 15, fc = l >> 4;
#pragma unroll
    for (int f = 0; f < 4; ++f) {
      const int ra = wm * 64 + f * 16 + frow;
      aoff[f] = ra * 64 + ((fc ^ ((ra >> 1) & 3)) * 16);
      const int rb = wn * 64 + f * 16 + frow;
      boff[f] = rb * 64 + ((fc ^ ((rb >> 1) & 3)) * 16);
    }
  }

  f32x4 acc[4][4];
#pragma unroll
  for (int i = 0; i < 4; ++i)
#pragma unroll
    for (int j = 0; j < 4; ++j) acc[i][j] = (f32x4){0.f, 0.f, 0.f, 0.f};

  for (int k0 = 0; k0 < 1024; k0 += 32) {
    __syncthreads();  // previous frag reads done
    const int scA = SPLIT_IN ? ((((k0 >> 6) << 16) + (k0 & 63)) * 2) : (k0 * 2);
    const int scB = k0 * 2;
    gload16(Ah + offA[0] + scA, (char*)sAhi + w * 1024);
    gload16(Ah + offA[1] + scA, (char*)sAhi + 4096 + w * 1024);
    gload16(Al + offA[0] + scA, (char*)sAlo + w * 1024);
    gload16(Al + offA[1] + scA, (char*)sAlo + 4096 + w * 1024);
    gload16(Bh + offB[0] + scB, (char*)sBhi + w * 1024);
    gload16(Bh + offB[1] + scB, (char*)sBhi + 4096 + w * 1024);
    gload16(Bl + offB[0] + scB, (char*)sBlo + w * 1024);
    gload16(Bl + offB[1] + scB, (char*)sBlo + 4096 + w * 1024);
    __syncthreads();  // drains vmcnt: tiles ready

    bf16x8 fah[4], fal[4], fbh[4], fbl[4];
#pragma unroll
    for (int f = 0; f < 4; ++f) {
      fah[f] = *(const bf16x8*)((const char*)sAhi + aoff[f]);
      fal[f] = *(const bf16x8*)((const char*)sAlo + aoff[f]);
      fbh[f] = *(const bf16x8*)((const char*)sBhi + boff[f]);
      fbl[f] = *(const bf16x8*)((const char*)sBlo + boff[f]);
    }
#pragma unroll
    for (int fi = 0; fi < 4; ++fi)
#pragma unroll
      for (int fj = 0; fj < 4; ++fj) {
        acc[fi][fj] = __builtin_amdgcn_mfma_f32_16x16x32_bf16(
            fah[fi], fbh[fj], acc[fi][fj], 0, 0, 0);
        acc[fi][fj] = __builtin_amdgcn_mfma_f32_16x16x32_bf16(
            fah[fi], fbl[fj], acc[fi][fj], 0, 0, 0);
        acc[fi][fj] = __builtin_amdgcn_mfma_f32_16x16x32_bf16(
            fal[fi], fbh[fj], acc[fi][fj], 0, 0, 0);
      }
  }

  // epilogue: C/D layout col = lane&15, row = (lane>>4)*4 + r  [m89-verified]
  const float* __restrict__ bias = P.bias[z];
  float* __restrict__ Y = P.y[z];
  float bv[4];
#pragma unroll
  for (int fj = 0; fj < 4; ++fj)
    bv[fj] = bias[bn0 + wn * 64 + fj * 16 + (l & 15)];
#pragma unroll
  for (int fi = 0; fi < 4; ++fi)
#pragma unroll
    for (int fj = 0; fj < 4; ++fj) {
      const int n = bn0 + wn * 64 + fj * 16 + (l & 15);
#pragma unroll
      for (int r = 0; r < 4; ++r) {
        const int m = bm0 + wm * 64 + fi * 16 + (l >> 4) * 4 + r;
        const float val = acc[fi][fj][r] + bv[fj];
        if constexpr (SPLIT_OUT) Y[split_idx(m, n)] = val;
        else Y[m * 1024 + n] = val;
      }
    }
}

// ---------------------------------------------------------------------------
// Round-1 fp32 GEMM (fallback when ws is small).
// ---------------------------------------------------------------------------
struct GemmPtrs {
  const float* x[6]; const float* w[6]; const float* b[6]; float* y[6];
};
template<bool SPLIT_IN, bool SPLIT_OUT>
__global__ __launch_bounds__(256, 4) void gemm_kernel(GemmPtrs P) {
  const int z = blockIdx.z;
  const float* __restrict__ A = P.x[z];
  const float* __restrict__ W = P.w[z];
  const float* __restrict__ bias = P.b[z];
  float* __restrict__ Y = P.y[z];
  __shared__ float As[16][132];
  __shared__ float Bs[16][132];
  const int t = threadIdx.x;
  const int tx = t & 15, ty = t >> 4;
  const int bm0 = blockIdx.y * 128, bn0 = blockIdx.x * 128;
  float acc[8][8];
#pragma unroll
  for (int ii = 0; ii < 8; ++ii)
#pragma unroll
    for (int jj = 0; jj < 8; ++jj) acc[ii][jj] = 0.f;
  for (int k0 = 0; k0 < 1024; k0 += 16) {
    float4 av[2], bv[2];
#pragma unroll
    for (int q = 0; q < 2; ++q) {
      const int f = q * 256 + t, row = f >> 2, k4 = f & 3, gk = k0 + k4 * 4;
      if constexpr (SPLIT_IN) av[q] = *(const float4*)&A[split_idx(bm0 + row, gk)];
      else av[q] = *(const float4*)&A[(bm0 + row) * 1024 + gk];
      bv[q] = *(const float4*)&W[(bn0 + row) * 1024 + gk];
    }
    __syncthreads();
#pragma unroll
    for (int q = 0; q < 2; ++q) {
      const int f = q * 256 + t, row = f >> 2, k4 = f & 3;
      As[k4 * 4 + 0][row] = av[q].x; As[k4 * 4 + 1][row] = av[q].y;
      As[k4 * 4 + 2][row] = av[q].z; As[k4 * 4 + 3][row] = av[q].w;
      Bs[k4 * 4 + 0][row] = bv[q].x; Bs[k4 * 4 + 1][row] = bv[q].y;
      Bs[k4 * 4 + 2][row] = bv[q].z; Bs[k4 * 4 + 3][row] = bv[q].w;
    }
    __syncthreads();
#pragma unroll
    for (int k = 0; k < 16; ++k) {
      const float4 a0 = *(const float4*)&As[k][ty * 4];
      const float4 a1 = *(const float4*)&As[k][64 + ty * 4];
      const float4 b0 = *(const float4*)&Bs[k][tx * 4];
      const float4 b1 = *(const float4*)&Bs[k][64 + tx * 4];
      const float am[8] = {a0.x, a0.y, a0.z, a0.w, a1.x, a1.y, a1.z, a1.w};
      const float bn[8] = {b0.x, b0.y, b0.z, b0.w, b1.x, b1.y, b1.z, b1.w};
#pragma unroll
      for (int ii = 0; ii < 8; ++ii)
#pragma unroll
        for (int jj = 0; jj < 8; ++jj)
          acc[ii][jj] = fmaf(am[ii], bn[jj], acc[ii][jj]);
    }
  }
  const float4 bia0 = *(const float4*)&bias[bn0 + tx * 4];
  const float4 bia1 = *(const float4*)&bias[bn0 + 64 + tx * 4];
  const float bb[8] = {bia0.x, bia0.y, bia0.z, bia0.w,
                       bia1.x, bia1.y, bia1.z, bia1.w};
#pragma unroll
  for (int ii = 0; ii < 8; ++ii) {
    const int m = bm0 + ((ii < 4) ? (ty * 4 + ii) : (64 + ty * 4 + ii - 4));
    float4 r0, r1;
    r0.x = acc[ii][0] + bb[0]; r0.y = acc[ii][1] + bb[1];
    r0.z = acc[ii][2] + bb[2]; r0.w = acc[ii][3] + bb[3];
    r1.x = acc[ii][4] + bb[4]; r1.y = acc[ii][5] + bb[5];
    r1.z = acc[ii][6] + bb[6]; r1.w = acc[ii][7] + bb[7];
    if constexpr (SPLIT_OUT) {
      *(float4*)&Y[split_idx(m, bn0 + tx * 4)] = r0;
      *(float4*)&Y[split_idx(m, bn0 + 64 + tx * 4)] = r1;
    } else {
      *(float4*)&Y[m * 1024 + bn0 + tx * 4] = r0;
      *(float4*)&Y[m * 1024 + bn0 + 64 + tx * 4] = r1;
    }
  }
}

// ---------------------------------------------------------------------------
// Fused decay attention, v2.
// Grid (S/16, B*H, 2 paths), block 256 = 4 waves; wave w owns rows
// i = q0 + w + 4*rr, rr=0..3.  Scores kept in registers v[4][16]
// (j = tt*64 + lane).  Scans made independent (16-way ILP), chunk-prefix in
// registers.  K/V staged block-wide per 64-key chunk; Q staged in LDS.
// ---------------------------------------------------------------------------
__device__ __forceinline__ float wmax64(float x) {
#pragma unroll
  for (int off = 32; off > 0; off >>= 1) x = fmaxf(x, __shfl_xor(x, off));
  return x;
}
__device__ __forceinline__ float wsum64(float x) {
#pragma unroll
  for (int off = 32; off > 0; off >>= 1) x += __shfl_xor(x, off);
  return x;
}

template<bool BF16OUT>
__global__ __launch_bounds__(256, 3) void decay_attn2(
    const float* __restrict__ qm, const float* __restrict__ km,
    const float* __restrict__ vm, const float* __restrict__ qc,
    const float* __restrict__ kc, const float* __restrict__ vc,
    float* __restrict__ om, float* __restrict__ oc,
    ushort* __restrict__ omh, ushort* __restrict__ oml,
    ushort* __restrict__ och, ushort* __restrict__ ocl,
    const float* __restrict__ gammas) {
  __shared__ float kvT[64][65];     // [d][j_local], 2-way-free
  __shared__ float q_s[16][64];     // block's q rows
  __shared__ float p_s[4][4][64];   // per-wave per-row p chunk for PV

  const int t = threadIdx.x, l = t & 63, w = t >> 6;
  const int bh = blockIdx.y, h = bh & 15;
  const int q0 = blockIdx.x * 16;
  const int path = blockIdx.z;
  const int base = bh << 16;
  const float* Q = (path ? qc : qm) + base;
  const float* K = (path ? kc : km) + base;
  const float* V = (path ? vc : vm) + base;
  const float g = -log1pf(__expf(gammas[h]));

  // stage q rows
  {
    const int row = t >> 4, d4 = t & 15;
    *(float4*)&q_s[row][d4 * 4] = *(const float4*)&Q[(q0 + row) * 64 + d4 * 4];
  }
  const int nchunks = (q0 >> 6) + 1;  // <= 16

  float v[4][16];
#pragma unroll
  for (int rr = 0; rr < 4; ++rr)
#pragma unroll
    for (int tt = 0; tt < 16; ++tt) v[rr][tt] = 0.f;

  // ---- phase 1: scores ----
#pragma unroll 16
  for (int c = 0; c < 16; ++c) {
    if (c >= nchunks) break;
    if (c > 0) __syncthreads();
#pragma unroll
    for (int p = 0; p < 4; ++p) {
      const int f = p * 256 + t, j = f >> 4, d4 = f & 15;
      const float4 val = *(const float4*)&K[((c << 6) + j) * 64 + d4 * 4];
      kvT[d4 * 4 + 0][j] = val.x; kvT[d4 * 4 + 1][j] = val.y;
      kvT[d4 * 4 + 2][j] = val.z; kvT[d4 * 4 + 3][j] = val.w;
    }
    __syncthreads();
    float dots[4] = {0.f, 0.f, 0.f, 0.f};
#pragma unroll
    for (int d4 = 0; d4 < 16; ++d4) {
      const float k0v = kvT[d4 * 4 + 0][l], k1v = kvT[d4 * 4 + 1][l];
      const float k2v = kvT[d4 * 4 + 2][l], k3v = kvT[d4 * 4 + 3][l];
#pragma unroll
      for (int rr = 0; rr < 4; ++rr) {
        const float4 q4 = *(const float4*)&q_s[w + 4 * rr][d4 * 4];
        dots[rr] = fmaf(q4.x, k0v,
                   fmaf(q4.y, k1v, fmaf(q4.z, k2v, fmaf(q4.w, k3v, dots[rr]))));
      }
    }
#pragma unroll
    for (int rr = 0; rr < 4; ++rr) v[rr][c] = dots[rr] * 0.125f;
  }

  // ---- phase 2: decay softmax per row (registers + shfl) ----
#pragma unroll
  for (int rr = 0; rr < 4; ++rr) {
    const int i = q0 + w + 4 * rr;
    float m1 = -INFINITY;
#pragma unroll
    for (int g4 = 0; g4 < 4; ++g4) if (g4 * 4 < nchunks) {
#pragma unroll
      for (int u = 0; u < 4; ++u) {
        const int tt = g4 * 4 + u, j = tt * 64 + l;
        m1 = fmaxf(m1, (j <= i) ? v[rr][tt] : -INFINITY);
      }
    }
    m1 = wmax64(m1);

    float x[16], T[16];
    float zl = 0.f;
#pragma unroll
    for (int g4 = 0; g4 < 4; ++g4) if (g4 * 4 < nchunks) {
#pragma unroll
      for (int u = 0; u < 4; ++u) {
        const int tt = g4 * 4 + u, j = tt * 64 + l;
        x[tt] = (j <= i) ? __expf(v[rr][tt] - m1) : 0.f;
        zl += x[tt];
      }
    }
    const float rz1 = 1.f / wsum64(zl);
#pragma unroll
    for (int g4 = 0; g4 < 4; ++g4) if (g4 * 4 < nchunks) {
#pragma unroll
      for (int u = 0; u < 4; ++u) x[g4 * 4 + u] *= rz1;
    }
    // independent inclusive scans (ILP across tt)
#pragma unroll
    for (int g4 = 0; g4 < 4; ++g4) if (g4 * 4 < nchunks) {
#pragma unroll
      for (int u = 0; u < 4; ++u) {
        const int tt = g4 * 4 + u;
#pragma unroll
        for (int off = 1; off < 64; off <<= 1) {
          const float nb = __shfl_up(x[tt], off);
          if (l >= off) x[tt] += nb;
        }
      }
    }
#pragma unroll
    for (int g4 = 0; g4 < 4; ++g4) if (g4 * 4 < nchunks) {
#pragma unroll
      for (int u = 0; u < 4; ++u) T[g4 * 4 + u] = __shfl(x[g4 * 4 + u], 63);
    }
    // chunk-prefix in registers; tot matches reference's sum of normalized p
    float tot = 0.f;
#pragma unroll
    for (int g4 = 0; g4 < 4; ++g4) if (g4 * 4 < nchunks) {
#pragma unroll
      for (int u = 0; u < 4; ++u) tot += T[g4 * 4 + u];
    }
    float run = 0.f, m2 = -INFINITY;
#pragma unroll
    for (int g4 = 0; g4 < 4; ++g4) if (g4 * 4 < nchunks) {
#pragma unroll
      for (int u = 0; u < 4; ++u) {
        const int tt = g4 * 4 + u, j = tt * 64 + l;
        const float cum = run + x[tt];
        run += T[tt];
        const float rem = fmaxf(tot - cum, 0.f);
        const float dist = sqrtf(fmaxf(rem * (float)(i - j), 0.f));
        float eff = __expf(dist * g);
        eff = fminf(fmaxf(eff, 1e-5f), 1e5f);
        const float s2 = (j <= i) ? v[rr][tt] * eff : -INFINITY;
        v[rr][tt] = s2;
        m2 = fmaxf(m2, s2);
      }
    }
    m2 = wmax64(m2);
    float z2 = 0.f;
#pragma unroll
    for (int g4 = 0; g4 < 4; ++g4) if (g4 * 4 < nchunks) {
#pragma unroll
      for (int u = 0; u < 4; ++u) {
        const int tt = g4 * 4 + u;
        const float e2 = __expf(v[rr][tt] - m2);
        v[rr][tt] = e2;
        z2 += e2;
      }
    }
    const float rz2 = 1.f / wsum64(z2);
#pragma unroll
    for (int g4 = 0; g4 < 4; ++g4) if (g4 * 4 < nchunks) {
#pragma unroll
      for (int u = 0; u < 4; ++u) v[rr][g4 * 4 + u] *= rz2;
    }
  }

  // ---- phase 3: PV ----
  float acc[4] = {0.f, 0.f, 0.f, 0.f};
#pragma unroll 16
  for (int c = 0; c < 16; ++c) {
    if (c >= nchunks) break;
    __syncthreads();  // kvT/p_s consumers done (covers phase-1 readers too)
#pragma unroll
    for (int p = 0; p < 4; ++p) {
      const int f = p * 256 + t, j = f >> 4, d4 = f & 15;
      const float4 val = *(const float4*)&V[((c << 6) + j) * 64 + d4 * 4];
      kvT[d4 * 4 + 0][j] = val.x; kvT[d4 * 4 + 1][j] = val.y;
      kvT[d4 * 4 + 2][j] = val.z; kvT[d4 * 4 + 3][j] = val.w;
    }
#pragma unroll
    for (int rr = 0; rr < 4; ++rr) p_s[w][rr][l] = v[rr][c];
    __syncthreads();
#pragma unroll
    for (int j4 = 0; j4 < 16; ++j4) {
      const float v0 = kvT[l][j4 * 4 + 0], v1 = kvT[l][j4 * 4 + 1];
      const float v2 = kvT[l][j4 * 4 + 2], v3 = kvT[l][j4 * 4 + 3];
#pragma unroll
      for (int rr = 0; rr < 4; ++rr) {
        const float4 p4 = *(const float4*)&p_s[w][rr][j4 * 4];
        acc[rr] = fmaf(p4.x, v0,
                  fmaf(p4.y, v1, fmaf(p4.z, v2, fmaf(p4.w, v3, acc[rr]))));
      }
    }
  }

#pragma unroll
  for (int rr = 0; rr < 4; ++rr) {
    const int i = q0 + w + 4 * rr;
    const int idx = base + i * 64 + l;
    if constexpr (BF16OUT) {
      const ushort hb = bf16_rne(acc[rr]);
      const ushort lb = bf16_rne(acc[rr] - bf16f(hb));
      (path ? och : omh)[idx] = hb;
      (path ? ocl : oml)[idx] = lb;
    } else {
      (path ? oc : om)[idx] = acc[rr];
    }
  }
}

// ---------------------------------------------------------------------------
extern "C" void kernel_launch(void* const* d_in, const int* in_sizes, int n_in,
                              void* d_out, int out_size, void* d_ws,
                              size_t ws_size, hipStream_t stream) {
  (void)in_sizes; (void)n_in; (void)out_size;

  const float* X[6];
  for (int i = 0; i < 6; ++i) X[i] = (const float*)d_in[i];
  // weights/biases: d_in[7..22], gammas d_in[23]
  const float* Wt[8]; const float* Bs[8];
  for (int i = 0; i < 8; ++i) {
    Wt[i] = (const float*)d_in[7 + 2 * i];
    Bs[i] = (const float*)d_in[8 + 2 * i];
  }
  const float* gam = (const float*)d_in[23];
  float* out_mean = (float*)d_out;
  float* out_cov = out_mean + (size_t)NTOK * 1024;

  const size_t MB = 1024ull * 1024ull;
  const size_t NEED = 224ull * MB;
  char* ws = (char*)d_ws;

  if (ws_size >= NEED) {
    // ---- big path: split-bf16 MFMA GEMMs ----
    ushort* Xhi = (ushort*)(ws + 0);          // 6 x 8MB
    ushort* Xlo = (ushort*)(ws + 48 * MB);    // 6 x 8MB
    ushort* Whi = (ushort*)(ws + 96 * MB);    // 8 x 2MB
    ushort* Wlo = (ushort*)(ws + 112 * MB);   // 8 x 2MB
    float* QKV = (float*)(ws + 128 * MB);     // 6 x 16MB (head-split fp32)
    // attn bf16 outputs alias the X region (X consumed before attn runs)
    ushort* OMh = (ushort*)(ws + 0 * MB);
    ushort* OMl = (ushort*)(ws + 8 * MB);
    ushort* OCh = (ushort*)(ws + 16 * MB);
    ushort* OCl = (ushort*)(ws + 24 * MB);

    const size_t XE = 4194304, WE = 1048576, QE = 4194304;

    ConvP C = {};
    for (int i = 0; i < 6; ++i) {
      C.s[i] = (const float4*)X[i];
      C.hi[i] = Xhi + (size_t)i * XE;
      C.lo[i] = Xlo + (size_t)i * XE;
      C.n4[i] = (int)(XE / 4);
    }
    for (int i = 0; i < 8; ++i) {
      C.s[6 + i] = (const float4*)Wt[i];
      C.hi[6 + i] = Whi + (size_t)i * WE;
      C.lo[6 + i] = Wlo + (size_t)i * WE;
      C.n4[6 + i] = (int)(WE / 4);
    }
    convert_split<<<dim3(4096, 1, 14), 256, 0, stream>>>(C);

    MG Pin = {};
    for (int z = 0; z < 6; ++z) {
      Pin.ah[z] = (const char*)(Xhi + (size_t)z * XE);
      Pin.al[z] = (const char*)(Xlo + (size_t)z * XE);
      Pin.bh[z] = (const char*)(Whi + (size_t)z * WE);
      Pin.bl[z] = (const char*)(Wlo + (size_t)z * WE);
      Pin.bias[z] = Bs[z];
      Pin.y[z] = QKV + (size_t)z * QE;
    }
    gemm_mfma<false, true><<<dim3(8, 32, 6), 256, 0, stream>>>(Pin);

    float* qm = QKV + 0 * QE; float* qc = QKV + 1 * QE;
    float* km = QKV + 2 * QE; float* kc = QKV + 3 * QE;
    float* vm = QKV + 4 * QE; float* vc = QKV + 5 * QE;
    decay_attn2<true><<<dim3(64, 64, 2), 256, 0, stream>>>(
        qm, km, vm, qc, kc, vc, nullptr, nullptr, OMh, OMl, OCh, OCl, gam);

    MG Pout = {};
    Pout.ah[0] = (const char*)OMh; Pout.al[0] = (const char*)OMl;
    Pout.bh[0] = (const char*)(Whi + 6 * WE);
    Pout.bl[0] = (const char*)(Wlo + 6 * WE);
    Pout.bias[0] = Bs[6]; Pout.y[0] = out_mean;
    Pout.ah[1] = (const char*)OCh; Pout.al[1] = (const char*)OCl;
    Pout.bh[1] = (const char*)(Whi + 7 * WE);
    Pout.bl[1] = (const char*)(Wlo + 7 * WE);
    Pout.bias[1] = Bs[7]; Pout.y[1] = out_cov;
    gemm_mfma<true, false><<<dim3(8, 32, 2), 256, 0, stream>>>(Pout);
  } else {
    // ---- fallback: round-1 fp32 GEMMs + new attention ----
    float* qkv = (float*)ws;                  // 6 x 16MB
    float* om = (float*)(ws + 96 * MB);
    float* ocv = (float*)(ws + 112 * MB);
    const size_t QE = 4194304;

    GemmPtrs Pin = {};
    for (int z = 0; z < 6; ++z) {
      Pin.x[z] = X[z]; Pin.w[z] = Wt[z]; Pin.b[z] = Bs[z];
      Pin.y[z] = qkv + (size_t)z * QE;
    }
    gemm_kernel<false, true><<<dim3(8, 32, 6), 256, 0, stream>>>(Pin);

    decay_attn2<false><<<dim3(64, 64, 2), 256, 0, stream>>>(
        qkv + 0 * QE, qkv + 2 * QE, qkv + 4 * QE, qkv + 1 * QE, qkv + 3 * QE,
        qkv + 5 * QE, om, ocv, nullptr, nullptr, nullptr, nullptr, gam);

    GemmPtrs Pout = {};
    Pout.x[0] = om; Pout.w[0] = Wt[6]; Pout.b[0] = Bs[6]; Pout.y[0] = out_mean;
    Pout.x[1] = ocv; Pout.w[1] = Wt[7]; Pout.b[1] = Bs[7]; Pout.y[1] = out_cov;
    gemm_kernel<true, false><<<dim3(8, 32, 2), 256, 0, stream>>>(Pout);
  }
}